// Round 1
// 837.683 us; speedup vs baseline: 1.0388x; 1.0388x over previous
//
#include <hip/hip_runtime.h>

#define N_NODES 8192
#define N_EDGES 262144
#define DIM 128
#define NREP 64  // facc replicas to spread atomic contention

typedef float fv4 __attribute__((ext_vector_type(4)));

// ---------------- degree histogram (int) ----------------
__global__ void k_deg(const int* __restrict__ col, int* __restrict__ deg) {
    int e = blockIdx.x * blockDim.x + threadIdx.x;
    if (e < N_EDGES) atomicAdd(&deg[col[e]], 1);
}

// ---------------- scan + dinv: rowptr[8193] = exclusive scan(deg), dinv = rsqrt(deg+1) ----------------
// shfl-based wave scan: 2 barriers instead of 20 (whole GPU idles behind this block).
__global__ __launch_bounds__(1024) void k_scan(const int* __restrict__ deg,
                                               int* __restrict__ rowptr,
                                               float* __restrict__ dinv) {
    __shared__ int wsum[16];
    __shared__ int wpre[16];
    int t = threadIdx.x;
    int base = t * 8;
    int v[8];
    int s = 0;
    #pragma unroll
    for (int i = 0; i < 8; ++i) {
        int d = deg[base + i];
        dinv[base + i] = rsqrtf((float)d + 1.0f);  // +1 = self-loop
        v[i] = s; s += d;
    }
    int lane = t & 63, wv = t >> 6;
    int incl = s;  // inclusive scan of per-thread sums within the wave
    #pragma unroll
    for (int off = 1; off < 64; off <<= 1) {
        int n = __shfl_up(incl, off);
        if (lane >= off) incl += n;
    }
    if (lane == 63) wsum[wv] = incl;
    __syncthreads();
    if (t == 0) {
        int a = 0;
        #pragma unroll
        for (int i = 0; i < 16; ++i) { wpre[i] = a; a += wsum[i]; }
        rowptr[8192] = a;
    }
    __syncthreads();
    int ebase = wpre[wv] + incl - s;  // exclusive prefix for this thread
    #pragma unroll
    for (int i = 0; i < 8; ++i) rowptr[base + i] = ebase + v[i];
}

// ---------------- CSR fill: srcs grouped by target node ----------------
__global__ void k_fill(const int* __restrict__ rows, const int* __restrict__ cols,
                       const int* __restrict__ rowptr, int* __restrict__ cnt,
                       int* __restrict__ srcs) {
    int e = blockIdx.x * blockDim.x + threadIdx.x;
    if (e < N_EDGES) {
        int c = cols[e];
        int p = atomicAdd(&cnt[c], 1);
        srcs[rowptr[c] + p] = rows[e];
    }
}

// ---------------- dense GEMM: out[row] = dinv[row] * (x[row] @ W) ----------------
__global__ __launch_bounds__(256) void k_gemm(const float* __restrict__ x,
                                              const float* __restrict__ W,
                                              const float* __restrict__ dinv,
                                              float* __restrict__ out) {
    __shared__ float4 Wl[128 * 32];  // Wl[k*32+q] = W[k, 4q..4q+3]
    int t = threadIdx.x;
    const float4* W4 = (const float4*)W;
    for (int i = t; i < 128 * 32; i += 256) Wl[i] = W4[i];
    __syncthreads();

    int q  = t & 31;
    int rg = t >> 5;
    int row0 = blockIdx.x * 32;
    for (int p = 0; p < 4; ++p) {
        int row = row0 + p * 8 + rg;
        const float4* xr = (const float4*)(x + (size_t)row * DIM);
        float4 acc = {0.f, 0.f, 0.f, 0.f};
        #pragma unroll
        for (int k4 = 0; k4 < 32; ++k4) {
            float4 xv = xr[k4];
            float4 w0 = Wl[(k4 * 4 + 0) * 32 + q];
            float4 w1 = Wl[(k4 * 4 + 1) * 32 + q];
            float4 w2 = Wl[(k4 * 4 + 2) * 32 + q];
            float4 w3 = Wl[(k4 * 4 + 3) * 32 + q];
            acc.x += xv.x * w0.x + xv.y * w1.x + xv.z * w2.x + xv.w * w3.x;
            acc.y += xv.x * w0.y + xv.y * w1.y + xv.z * w2.y + xv.w * w3.y;
            acc.z += xv.x * w0.z + xv.y * w1.z + xv.z * w2.z + xv.w * w3.z;
            acc.w += xv.x * w0.w + xv.y * w1.w + xv.z * w2.w + xv.w * w3.w;
        }
        float s = dinv[row];
        acc.x *= s; acc.y *= s; acc.z *= s; acc.w *= s;
        ((float4*)(out + (size_t)row * DIM))[q] = acc;
    }
}

// ---------------- neighbor gather core ----------------
// srcs indices read 4-at-a-time as one aligned int4 (one uniform 16B fetch per chunk
// instead of 4 dependent scalar fetches); two accumulator chains for ILP.
__device__ __forceinline__ float2 gather_row(const float2* __restrict__ H,
                                             const int* __restrict__ srcs,
                                             int beg, int end, int node, int lane) {
    float2 a0 = H[(size_t)node * 64 + lane];  // self-loop term
    float2 a1 = {0.f, 0.f};
    int j = beg;
    int npre = (4 - (beg & 3)) & 3;
    if (npre > end - beg) npre = end - beg;
    for (int p = 0; p < npre; ++p, ++j) {
        float2 v = H[(size_t)srcs[j] * 64 + lane];
        a0.x += v.x; a0.y += v.y;
    }
    for (; j + 3 < end; j += 4) {
        int4 s4 = *reinterpret_cast<const int4*>(srcs + j);  // 16B-aligned: j%4==0
        float2 v0 = H[(size_t)s4.x * 64 + lane];
        float2 v1 = H[(size_t)s4.y * 64 + lane];
        float2 v2 = H[(size_t)s4.z * 64 + lane];
        float2 v3 = H[(size_t)s4.w * 64 + lane];
        a0.x += v0.x + v2.x; a0.y += v0.y + v2.y;
        a1.x += v1.x + v3.x; a1.y += v1.y + v3.y;
    }
    for (; j < end; ++j) {
        float2 v = H[(size_t)srcs[j] * 64 + lane];
        a1.x += v.x; a1.y += v.y;
    }
    a0.x += a1.x; a0.y += a1.y;
    return a0;
}

// ---------------- layer-1 gather: out[c] = relu(dinv[c]*(sum h[srcs] + h[c]) + b) ----------------
__global__ __launch_bounds__(256) void k_gather(const float* __restrict__ h,
                                                const int* __restrict__ srcs,
                                                const int* __restrict__ rowptr,
                                                const float* __restrict__ dinv,
                                                const float* __restrict__ b,
                                                float* __restrict__ out) {
    int t = threadIdx.x;
    int lane = t & 63;
    int node = blockIdx.x * 4 + (t >> 6);
    float2 acc = gather_row((const float2*)h, srcs, rowptr[node], rowptr[node + 1], node, lane);
    float s = dinv[node];
    float2 bv = ((const float2*)b)[lane];
    float2 o;
    o.x = fmaxf(s * acc.x + bv.x, 0.f);
    o.y = fmaxf(s * acc.y + bv.y, 0.f);
    ((float2*)(out + (size_t)node * DIM))[lane] = o;
}

// ---------------- fused layer-2 gather + fc1 partial ----------------
// Per wave: e2 row for its node (gather, no relu) -> LDS, then stream this node's
// 128 fc1_w rows (nontemporal float4 — read-once data, keep L2 for gather operands),
// reduce, 128 atomics per block spread over NREP replicas.
__global__ __launch_bounds__(256) void k_gfc(const float* __restrict__ h,
                                             const int* __restrict__ srcs,
                                             const int* __restrict__ rowptr,
                                             const float* __restrict__ dinv,
                                             const float* __restrict__ b,
                                             const float* __restrict__ w,
                                             float* __restrict__ facc_r) {
    __shared__ float oL[4][128];
    __shared__ fv4 red4[4][32];
    int t = threadIdx.x;
    int lane = t & 63;
    int wid = t >> 6;
    int node = blockIdx.x * 4 + wid;
    float2 acc = gather_row((const float2*)h, srcs, rowptr[node], rowptr[node + 1], node, lane);
    float s = dinv[node];
    float2 bv = ((const float2*)b)[lane];
    float2 o = { s * acc.x + bv.x, s * acc.y + bv.y };  // e2 row (no relu)
    ((float2*)oL[wid])[lane] = o;
    __syncthreads();

    // phase 2: facc[j] += sum_k e2[node,k] * w[node*128+k, j]
    int q  = lane & 31;   // j-quad
    int kh = lane >> 5;   // which of 2 rows this half-wave covers
    size_t rowbase = (size_t)node * 128;
    fv4 a4 = {0.f, 0.f, 0.f, 0.f};
    #pragma unroll 8
    for (int k2 = 0; k2 < 64; ++k2) {
        int k = k2 * 2 + kh;
        float ok = oL[wid][k];
        const fv4* wp = (const fv4*)(w + (rowbase + k) * 128);
        fv4 wr = __builtin_nontemporal_load(wp + q);  // streamed once: don't pollute L2
        a4 += ok * wr;
    }
    a4.x += __shfl_xor(a4.x, 32);
    a4.y += __shfl_xor(a4.y, 32);
    a4.z += __shfl_xor(a4.z, 32);
    a4.w += __shfl_xor(a4.w, 32);
    if (lane < 32) red4[wid][q] = a4;
    __syncthreads();
    if (t < 128) {
        const float* rf = (const float*)red4;
        float val = (rf[t] + rf[128 + t]) + (rf[256 + t] + rf[384 + t]);
        atomicAdd(&facc_r[((blockIdx.x & (NREP - 1)) << 7) + t], val);
    }
}

// ---------------- MLP tail (reduces NREP facc replicas first) ----------------
__global__ __launch_bounds__(128) void k_tail(const float* __restrict__ facc_r,
                                              const float* __restrict__ fc1_b,
                                              const float* __restrict__ fc2_w,
                                              const float* __restrict__ fc2_b,
                                              const float* __restrict__ fc3_w,
                                              const float* __restrict__ fc3_b,
                                              float* __restrict__ out) {
    __shared__ float h1[128], red[128];
    int j = threadIdx.x;
    float a0 = 0.f;
    #pragma unroll
    for (int r = 0; r < NREP; ++r) a0 += facc_r[r * 128 + j];
    h1[j] = fmaxf(a0 + fc1_b[j], 0.f);
    __syncthreads();
    float a = 0.f;
    #pragma unroll 8
    for (int k = 0; k < 128; ++k) a += h1[k] * fc2_w[k * 128 + j];
    float h2 = fmaxf(a + fc2_b[j], 0.f);
    red[j] = h2 * fc3_w[j];
    __syncthreads();
    if (j == 0) {
        float s = 0.f;
        for (int k = 0; k < 128; ++k) s += red[k];
        out[0] = s + fc3_b[0];
    }
}

extern "C" void kernel_launch(void* const* d_in, const int* in_sizes, int n_in,
                              void* d_out, int out_size, void* d_ws, size_t ws_size,
                              hipStream_t stream) {
    const float* x     = (const float*)d_in[0];
    const int*   ei    = (const int*)d_in[1];
    const float* W1    = (const float*)d_in[2];
    const float* b1    = (const float*)d_in[3];
    const float* W2    = (const float*)d_in[4];
    const float* b2    = (const float*)d_in[5];
    const float* fc1_w = (const float*)d_in[6];
    const float* fc1_b = (const float*)d_in[7];
    const float* fc2_w = (const float*)d_in[8];
    const float* fc2_b = (const float*)d_in[9];
    const float* fc3_w = (const float*)d_in[10];
    const float* fc3_b = (const float*)d_in[11];
    const int* rows = ei;             // edge_index[0] = sources
    const int* cols = ei + N_EDGES;   // edge_index[1] = targets

    float* buf0   = (float*)d_ws;                 // h_scaled, 1M floats (4 MB)
    float* buf1   = buf0 + (size_t)N_NODES * DIM; // e1, 1M floats (4 MB)
    int*   degi   = (int*)(buf1 + (size_t)N_NODES * DIM); // 8192 (zeroed)
    int*   cnt    = degi + N_NODES;               // 8192 (zeroed)
    float* facc_r = (float*)(cnt + N_NODES);      // NREP*128 = 8192 (zeroed)
    float* dinv   = facc_r + NREP * DIM;          // 8192
    int*   rowptr = (int*)(dinv + N_NODES);       // 8193
    int*   srcs   = rowptr + N_NODES + 8;         // 262144 (16B-aligned)
    float* out    = (float*)d_out;

    // one memset covers degi + cnt + facc_r (contiguous, 96 KB)
    hipMemsetAsync(degi, 0, (2 * N_NODES) * sizeof(int) + NREP * DIM * sizeof(float), stream);

    // ---- graph preprocessing: degrees, norm, CSR by target ----
    k_deg<<<N_EDGES / 256, 256, 0, stream>>>(cols, degi);
    k_scan<<<1, 1024, 0, stream>>>(degi, rowptr, dinv);
    k_fill<<<N_EDGES / 256, 256, 0, stream>>>(rows, cols, rowptr, cnt, srcs);

    // ---- GCN layer 1: e1 = relu(conv(x, W1, b1)) ----
    k_gemm<<<N_NODES / 32, 256, 0, stream>>>(x, W1, dinv, buf0);
    k_gather<<<N_NODES / 4, 256, 0, stream>>>(buf0, srcs, rowptr, dinv, b1, buf1);

    // ---- GCN layer 2 gather fused with fc1 partial accumulation ----
    k_gemm<<<N_NODES / 32, 256, 0, stream>>>(buf1, W2, dinv, buf0);
    k_gfc<<<N_NODES / 4, 256, 0, stream>>>(buf0, srcs, rowptr, dinv, b2, fc1_w, facc_r);

    // ---- MLP tail ----
    k_tail<<<1, 128, 0, stream>>>(facc_r, fc1_b, fc2_w, fc2_b, fc3_w, fc3_b, out);
}